// Round 1
// baseline (335.654 us; speedup 1.0000x reference)
//
#include <hip/hip_runtime.h>
#include <hip/hip_bf16.h>

#define NB 2
#define NS 2048
#define NE 1024
#define NH 16
#define HD 64

typedef __hip_bfloat16 bf16;
typedef __attribute__((ext_vector_type(8))) short bf16x8;
typedef __attribute__((ext_vector_type(4))) float f32x4;

typedef __attribute__((address_space(3))) void* lds_p;
typedef const __attribute__((address_space(1))) void* glb_p;

#define MFMA16(a, b, c) __builtin_amdgcn_mfma_f32_16x16x32_bf16((a), (b), (c), 0, 0, 0)

__device__ __forceinline__ void gl_lds16(const void* g, void* l) {
    __builtin_amdgcn_global_load_lds((glb_p)g, (lds_p)l, 16, 0, 0);
}

__device__ __forceinline__ bf16x8 ldv8(const bf16* p) { return *(const bf16x8*)p; }

// ---------------- cast f32 -> bf16 (vectorized) ----------------
__global__ __launch_bounds__(256) void cast_bf16_k(const float* __restrict__ in,
                                                   bf16* __restrict__ out, int n4) {
    int i = blockIdx.x * 256 + threadIdx.x;
    if (i >= n4) return;
    float4 v = ((const float4*)in)[i];
    union { ushort4 u; bf16 b[4]; } pk;
    pk.b[0] = __float2bfloat16(v.x);
    pk.b[1] = __float2bfloat16(v.y);
    pk.b[2] = __float2bfloat16(v.z);
    pk.b[3] = __float2bfloat16(v.w);
    ((ushort4*)out)[i] = pk.u;
}

// ---------------- QKV GEMM: C[t,f] = sum_e x[t,e] * Wqkv[f,e] + bqkv[f] ----------------
// M=4096 (tokens), N=3072 (f), K=1024. 128x128 tile, BK=32, 4 waves of 64x64.
// Epilogue scatters into Q[b,h,s,d], K[b,h,s,d], Vt[b,h,d,s] (bf16).
__global__ __launch_bounds__(256) void qkv_gemm(const bf16* __restrict__ A,
                                                const bf16* __restrict__ Bm,
                                                const float* __restrict__ bqkv,
                                                bf16* __restrict__ Qb, bf16* __restrict__ Kb,
                                                bf16* __restrict__ Vtb) {
    __shared__ bf16 As[128 * 32];
    __shared__ bf16 Bs[128 * 32];
    const int brow = blockIdx.x * 128;
    const int bcol = blockIdx.y * 128;
    const int t = threadIdx.x;
    const int w = t >> 6, lane = t & 63;
    const int wr = (w >> 1) * 64, wc = (w & 1) * 64;
    const int lr = lane & 15, lh = lane >> 4;
    const int K = 1024;

    f32x4 acc[4][4];
#pragma unroll
    for (int m = 0; m < 4; ++m)
#pragma unroll
        for (int n = 0; n < 4; ++n) acc[m][n] = (f32x4){0.f, 0.f, 0.f, 0.f};

    const bf16* ga0 = A + (size_t)(brow + (t >> 2)) * K + (t & 3) * 8;
    const bf16* ga1 = A + (size_t)(brow + 64 + (t >> 2)) * K + (t & 3) * 8;
    const bf16* gb0 = Bm + (size_t)(bcol + (t >> 2)) * K + (t & 3) * 8;
    const bf16* gb1 = Bm + (size_t)(bcol + 64 + (t >> 2)) * K + (t & 3) * 8;
    bf16* la0 = As + t * 8;
    bf16* la1 = As + 2048 + t * 8;
    bf16* lb0 = Bs + t * 8;
    bf16* lb1 = Bs + 2048 + t * 8;

    for (int kt = 0; kt < K; kt += 32) {
        gl_lds16(ga0 + kt, la0);
        gl_lds16(ga1 + kt, la1);
        gl_lds16(gb0 + kt, lb0);
        gl_lds16(gb1 + kt, lb1);
        __syncthreads();
        bf16x8 af[4], bfv[4];
#pragma unroll
        for (int m = 0; m < 4; ++m) af[m] = ldv8(&As[(wr + m * 16 + lr) * 32 + lh * 8]);
#pragma unroll
        for (int n = 0; n < 4; ++n) bfv[n] = ldv8(&Bs[(wc + n * 16 + lr) * 32 + lh * 8]);
#pragma unroll
        for (int m = 0; m < 4; ++m)
#pragma unroll
            for (int n = 0; n < 4; ++n) acc[m][n] = MFMA16(af[m], bfv[n], acc[m][n]);
        __syncthreads();
    }

    // epilogue: f -> (h, which, d); which: 0=Q 1=K 2=V
#pragma unroll
    for (int n = 0; n < 4; ++n) {
        const int col = bcol + wc + n * 16 + lr;
        const int h = col / 192;
        const int r = col - h * 192;
        const int wh = r >> 6;
        const int d = r & 63;
        const float bq = bqkv[col];
#pragma unroll
        for (int m = 0; m < 4; ++m) {
            const int row0 = brow + wr + m * 16 + lh * 4;  // token base; i adds 0..3
            const int b = row0 >> 11;
            const int s0 = row0 & 2047;
            const size_t hb = (size_t)(b * NH + h) * (NS * HD);
            if (wh == 2) {
                alignas(8) bf16 tmp[4];
#pragma unroll
                for (int i = 0; i < 4; ++i) tmp[i] = __float2bfloat16(acc[m][n][i] + bq);
                *(ushort4*)(Vtb + hb + (size_t)d * NS + s0) = *(const ushort4*)tmp;
            } else {
                bf16* dst = (wh == 0 ? Qb : Kb) + hb + (size_t)s0 * HD + d;
#pragma unroll
                for (int i = 0; i < 4; ++i) dst[(size_t)i * HD] = __float2bfloat16(acc[m][n][i] + bq);
            }
        }
    }
}

// ---------------- fused attention ----------------
// grid (S/64, B*H), block 256 = 4 independent waves, each owns 16 q-rows.
// logits = (q.k + bias)*0.125, clip +-5, exp; no max-tracking needed (bounded).
__global__ __launch_bounds__(256) void attn_k(const bf16* __restrict__ Qb,
                                              const bf16* __restrict__ Kb,
                                              const bf16* __restrict__ Vtb,
                                              const float* __restrict__ bias,
                                              bf16* __restrict__ valsb) {
    const int bh = blockIdx.y;
    const int q0 = blockIdx.x * 64;
    const int w = threadIdx.x >> 6, lane = threadIdx.x & 63;
    const int lr = lane & 15, lh = lane >> 4;
    __shared__ bf16 Ps[4][16][72];  // +8 pad: bank-conflict-free b128 reads

    const bf16* Qp = Qb + (size_t)bh * NS * HD;
    const bf16* Kp = Kb + (size_t)bh * NS * HD;
    const bf16* Vp = Vtb + (size_t)bh * HD * NS;
    const float* Bp = bias + (size_t)bh * NS * NS;

    const int qw = q0 + w * 16;
    bf16x8 qf0 = ldv8(&Qp[(qw + lr) * HD + lh * 8]);
    bf16x8 qf1 = ldv8(&Qp[(qw + lr) * HD + 32 + lh * 8]);

    f32x4 acc_o[4];
    float rowsum[4];
#pragma unroll
    for (int n = 0; n < 4; ++n) acc_o[n] = (f32x4){0.f, 0.f, 0.f, 0.f};
#pragma unroll
    for (int i = 0; i < 4; ++i) rowsum[i] = 0.f;

    const float C1 = 0.18033688011112042f;  // 0.125 * log2(e)
    const float C2 = 7.2134752044448170f;   // 5 * log2(e)

    for (int kt = 0; kt < NS; kt += 64) {
        f32x4 s_acc[4];
#pragma unroll
        for (int n = 0; n < 4; ++n) s_acc[n] = (f32x4){0.f, 0.f, 0.f, 0.f};
#pragma unroll
        for (int n = 0; n < 4; ++n) {
            bf16x8 k0 = ldv8(&Kp[(kt + n * 16 + lr) * HD + lh * 8]);
            bf16x8 k1 = ldv8(&Kp[(kt + n * 16 + lr) * HD + 32 + lh * 8]);
            s_acc[n] = MFMA16(qf0, k0, s_acc[n]);
            s_acc[n] = MFMA16(qf1, k1, s_acc[n]);
        }
#pragma unroll
        for (int n = 0; n < 4; ++n) {
#pragma unroll
            for (int i = 0; i < 4; ++i) {
                const int qrow = qw + lh * 4 + i;
                float bval = Bp[(size_t)qrow * NS + kt + n * 16 + lr];
                float x = (s_acc[n][i] + bval) * C1;
                x = fminf(fmaxf(x, -C2), C2);
                float p = exp2f(x);
                rowsum[i] += p;
                Ps[w][lh * 4 + i][n * 16 + lr] = __float2bfloat16(p);
            }
        }
        bf16x8 pa0 = ldv8(&Ps[w][lr][lh * 8]);
        bf16x8 pa1 = ldv8(&Ps[w][lr][32 + lh * 8]);
#pragma unroll
        for (int n = 0; n < 4; ++n) {
            bf16x8 v0 = ldv8(&Vp[(size_t)(n * 16 + lr) * NS + kt + lh * 8]);
            bf16x8 v1 = ldv8(&Vp[(size_t)(n * 16 + lr) * NS + kt + 32 + lh * 8]);
            acc_o[n] = MFMA16(pa0, v0, acc_o[n]);
            acc_o[n] = MFMA16(pa1, v1, acc_o[n]);
        }
    }

#pragma unroll
    for (int i = 0; i < 4; ++i) {
#pragma unroll
        for (int mm = 1; mm < 16; mm <<= 1) rowsum[i] += __shfl_xor(rowsum[i], mm, 64);
    }
    float inv[4];
#pragma unroll
    for (int i = 0; i < 4; ++i) inv[i] = 1.0f / rowsum[i];

    const int b = bh >> 4, h = bh & 15;
#pragma unroll
    for (int n = 0; n < 4; ++n) {
#pragma unroll
        for (int i = 0; i < 4; ++i) {
            const int qrow = qw + lh * 4 + i;
            valsb[(size_t)(b * NS + qrow) * NE + h * HD + n * 16 + lr] =
                __float2bfloat16(acc_o[n][i] * inv[i]);
        }
    }
}

// ---------------- out GEMM: out[t,f] = sum_e vals[t,e] * Wo[f,e] + bo[f] ----------------
__global__ __launch_bounds__(256) void out_gemm(const bf16* __restrict__ A,
                                                const bf16* __restrict__ Bm,
                                                const float* __restrict__ bo,
                                                float* __restrict__ out) {
    __shared__ bf16 As[128 * 32];
    __shared__ bf16 Bs[128 * 32];
    const int brow = blockIdx.x * 128;
    const int bcol = blockIdx.y * 128;
    const int t = threadIdx.x;
    const int w = t >> 6, lane = t & 63;
    const int wr = (w >> 1) * 64, wc = (w & 1) * 64;
    const int lr = lane & 15, lh = lane >> 4;
    const int K = 1024;

    f32x4 acc[4][4];
#pragma unroll
    for (int m = 0; m < 4; ++m)
#pragma unroll
        for (int n = 0; n < 4; ++n) acc[m][n] = (f32x4){0.f, 0.f, 0.f, 0.f};

    const bf16* ga0 = A + (size_t)(brow + (t >> 2)) * K + (t & 3) * 8;
    const bf16* ga1 = A + (size_t)(brow + 64 + (t >> 2)) * K + (t & 3) * 8;
    const bf16* gb0 = Bm + (size_t)(bcol + (t >> 2)) * K + (t & 3) * 8;
    const bf16* gb1 = Bm + (size_t)(bcol + 64 + (t >> 2)) * K + (t & 3) * 8;
    bf16* la0 = As + t * 8;
    bf16* la1 = As + 2048 + t * 8;
    bf16* lb0 = Bs + t * 8;
    bf16* lb1 = Bs + 2048 + t * 8;

    for (int kt = 0; kt < K; kt += 32) {
        gl_lds16(ga0 + kt, la0);
        gl_lds16(ga1 + kt, la1);
        gl_lds16(gb0 + kt, lb0);
        gl_lds16(gb1 + kt, lb1);
        __syncthreads();
        bf16x8 af[4], bfv[4];
#pragma unroll
        for (int m = 0; m < 4; ++m) af[m] = ldv8(&As[(wr + m * 16 + lr) * 32 + lh * 8]);
#pragma unroll
        for (int n = 0; n < 4; ++n) bfv[n] = ldv8(&Bs[(wc + n * 16 + lr) * 32 + lh * 8]);
#pragma unroll
        for (int m = 0; m < 4; ++m)
#pragma unroll
            for (int n = 0; n < 4; ++n) acc[m][n] = MFMA16(af[m], bfv[n], acc[m][n]);
        __syncthreads();
    }

#pragma unroll
    for (int n = 0; n < 4; ++n) {
        const int col = bcol + wc + n * 16 + lr;
        const float bv = bo[col];
#pragma unroll
        for (int m = 0; m < 4; ++m) {
            const int row0 = brow + wr + m * 16 + lh * 4;
#pragma unroll
            for (int i = 0; i < 4; ++i) out[(size_t)(row0 + i) * NE + col] = acc[m][n][i] + bv;
        }
    }
}

extern "C" void kernel_launch(void* const* d_in, const int* in_sizes, int n_in,
                              void* d_out, int out_size, void* d_ws, size_t ws_size,
                              hipStream_t stream) {
    const float* x = (const float*)d_in[0];
    const float* attn_bias = (const float*)d_in[1];
    const float* Wqkv = (const float*)d_in[2];
    const float* bqkv = (const float*)d_in[3];
    const float* Wo = (const float*)d_in[4];
    const float* bo = (const float*)d_in[5];
    float* out = (float*)d_out;

    char* ws = (char*)d_ws;
    bf16* xb = (bf16*)(ws);                      // 8 MiB  [4096,1024]
    bf16* Wqkvb = (bf16*)(ws + (8u << 20));      // 6 MiB  [3072,1024]
    bf16* Wob = (bf16*)(ws + (14u << 20));       // 2 MiB  [1024,1024]
    bf16* Qb = (bf16*)(ws + (16u << 20));        // 8 MiB  [B,H,S,HD]
    bf16* Kb = (bf16*)(ws + (24u << 20));        // 8 MiB  [B,H,S,HD]
    bf16* Vtb = (bf16*)(ws + (32u << 20));       // 8 MiB  [B,H,HD,S]
    bf16* valsb = (bf16*)(ws + (40u << 20));     // 8 MiB  [B,S,H,HD]

    // casts
    cast_bf16_k<<<4096, 256, 0, stream>>>(x, xb, (NB * NS * NE) / 4);
    cast_bf16_k<<<3072, 256, 0, stream>>>(Wqkv, Wqkvb, (3 * NE * NE) / 4);
    cast_bf16_k<<<1024, 256, 0, stream>>>(Wo, Wob, (NE * NE) / 4);

    // QKV projection
    qkv_gemm<<<dim3(32, 24), 256, 0, stream>>>(xb, Wqkvb, bqkv, Qb, Kb, Vtb);

    // fused attention
    attn_k<<<dim3(NS / 64, NB * NH), 256, 0, stream>>>(Qb, Kb, Vtb, attn_bias, valsb);

    // output projection
    out_gemm<<<dim3(32, 8), 256, 0, stream>>>(valsb, Wob, bo, out);
}